// Round 1
// baseline (759.382 us; speedup 1.0000x reference)
//
#include <hip/hip_runtime.h>

// out = segment_sum(x, batch)  — softmax over a size-1 axis == 1, so the
// linear layer (W, b) is mathematically dead and x is summed directly.
//
// Layout: one wave (64 lanes) owns a contiguous chunk of ROWS_PER_WAVE rows.
// Lane l owns columns [2l, 2l+1] (float2 => 64 lanes * 8 B = 512 B = one row
// per wave-load, fully coalesced). batch is sorted, so the wave accumulates
// into registers while the segment id is unchanged and flushes with atomicAdd
// only at segment boundaries (~1 per 100 rows) and at chunk end.

#define C 128
#define ROWS_PER_WAVE 256
#define WAVES_PER_BLOCK 4
#define BLOCK_THREADS (WAVES_PER_BLOCK * 64)

__global__ __launch_bounds__(BLOCK_THREADS)
void segsum_kernel(const float* __restrict__ x,
                   const int* __restrict__ batch,
                   float* __restrict__ out,
                   int n_rows) {
    const int wave_id = blockIdx.x * WAVES_PER_BLOCK + (threadIdx.x >> 6);
    const int lane    = threadIdx.x & 63;

    int row0 = wave_id * ROWS_PER_WAVE;
    if (row0 >= n_rows) return;
    int row_end = row0 + ROWS_PER_WAVE;
    if (row_end > n_rows) row_end = n_rows;

    // x viewed as float2: row stride = C/2 = 64 float2 elements.
    const float2* __restrict__ xv = (const float2*)x;

    float2 acc = make_float2(0.0f, 0.0f);
    int cur_seg = batch[row0];   // same address across lanes -> broadcast

    for (int r = row0; r < row_end; ++r) {
        int seg = batch[r];
        if (seg != cur_seg) {                 // wave-uniform, rare (~1/100)
            float* o = out + cur_seg * C + 2 * lane;
            atomicAdd(o,     acc.x);
            atomicAdd(o + 1, acc.y);
            acc = make_float2(0.0f, 0.0f);
            cur_seg = seg;
        }
        float2 v = xv[(size_t)r * (C / 2) + lane];
        acc.x += v.x;
        acc.y += v.y;
    }
    float* o = out + cur_seg * C + 2 * lane;
    atomicAdd(o,     acc.x);
    atomicAdd(o + 1, acc.y);
}

extern "C" void kernel_launch(void* const* d_in, const int* in_sizes, int n_in,
                              void* d_out, int out_size, void* d_ws, size_t ws_size,
                              hipStream_t stream) {
    const float* x     = (const float*)d_in[0];
    const int*   batch = (const int*)d_in[1];
    // d_in[2] = W, d_in[3] = b — unused: softmax over size-1 axis == 1.
    float* out = (float*)d_out;

    const int n_rows = in_sizes[0] / C;   // 1,000,000

    // d_out is poisoned to 0xAA before every launch; atomics need zeros.
    hipMemsetAsync(d_out, 0, (size_t)out_size * sizeof(float), stream);

    const int n_waves  = (n_rows + ROWS_PER_WAVE - 1) / ROWS_PER_WAVE;
    const int n_blocks = (n_waves + WAVES_PER_BLOCK - 1) / WAVES_PER_BLOCK;

    segsum_kernel<<<n_blocks, BLOCK_THREADS, 0, stream>>>(x, batch, out, n_rows);
}

// Round 2
// 665.607 us; speedup vs baseline: 1.1409x; 1.1409x over previous
//
#include <hip/hip_runtime.h>

// out = segment_sum(x, batch) — softmax over a size-1 axis == 1, so the
// linear layer (W, b) is mathematically dead and x is summed directly.
//
// Layout: one wave owns ROWS_PER_WAVE contiguous rows. Each load covers TWO
// rows: lanes 0-31 take the even row (float4 at col 4*(lane&31)), lanes 32-63
// the odd row. Segment id is tracked PER LANE (halves can disagree at a
// boundary); flush = 4 atomicAdds per lane, rare (~1 per 100 rows).
// Unroll 4 pairs (8 rows): 4 KB of x-loads in flight per wave before use.

#define C 128
#define ROWS_PER_WAVE 128
#define WAVES_PER_BLOCK 4
#define BLOCK_THREADS (WAVES_PER_BLOCK * 64)
#define UNROLL 4  // row-pairs per iteration

__device__ __forceinline__ void flush_acc(float* __restrict__ out, int seg,
                                          int col4, float4& acc) {
    float* o = out + (size_t)seg * C + 4 * col4;
    atomicAdd(o + 0, acc.x);
    atomicAdd(o + 1, acc.y);
    atomicAdd(o + 2, acc.z);
    atomicAdd(o + 3, acc.w);
    acc = make_float4(0.f, 0.f, 0.f, 0.f);
}

__global__ __launch_bounds__(BLOCK_THREADS)
void segsum_kernel(const float4* __restrict__ xv,   // x as float4: 32 per row
                   const int* __restrict__ batch,
                   float* __restrict__ out,
                   int n_rows) {
    const int wave = blockIdx.x * WAVES_PER_BLOCK + (threadIdx.x >> 6);
    const int lane = threadIdx.x & 63;
    const int half = lane >> 5;    // 0: even row of pair, 1: odd row
    const int col4 = lane & 31;    // float4 index within the row

    long row0 = (long)wave * ROWS_PER_WAVE;
    if (row0 >= n_rows) return;
    long row_end = row0 + ROWS_PER_WAVE;
    if (row_end > n_rows) row_end = n_rows;

    float4 acc = make_float4(0.f, 0.f, 0.f, 0.f);
    long first = row0 + half;
    if (first > n_rows - 1) first = n_rows - 1;
    int cur = batch[first];        // per-lane current segment

    long r = row0;
    // main: 4 pairs (8 rows) per iteration, all loads issued before use
    for (; r + 2 * UNROLL <= row_end; r += 2 * UNROLL) {
        float4 v[UNROLL];
        int    seg[UNROLL];
#pragma unroll
        for (int j = 0; j < UNROLL; ++j) {
            long row = r + 2 * j + half;
            v[j] = xv[row * (C / 4) + col4];
            int2 b2 = *(const int2*)(batch + r + 2 * j);  // 8B broadcast
            seg[j] = half ? b2.y : b2.x;
        }
#pragma unroll
        for (int j = 0; j < UNROLL; ++j) {
            if (seg[j] != cur) {               // rare, possibly divergent
                flush_acc(out, cur, col4, acc);
                cur = seg[j];
            }
            acc.x += v[j].x; acc.y += v[j].y;
            acc.z += v[j].z; acc.w += v[j].w;
        }
    }
    // tail: single pairs
    for (; r + 1 < row_end; r += 2) {
        long row = r + half;
        float4 v = xv[row * (C / 4) + col4];
        int2 b2 = *(const int2*)(batch + r);
        int  s  = half ? b2.y : b2.x;
        if (s != cur) {
            flush_acc(out, cur, col4, acc);
            cur = s;
        }
        acc.x += v.x; acc.y += v.y; acc.z += v.z; acc.w += v.w;
    }
    flush_acc(out, cur, col4, acc);
}

extern "C" void kernel_launch(void* const* d_in, const int* in_sizes, int n_in,
                              void* d_out, int out_size, void* d_ws, size_t ws_size,
                              hipStream_t stream) {
    const float* x     = (const float*)d_in[0];
    const int*   batch = (const int*)d_in[1];
    // d_in[2] = W, d_in[3] = b — unused: softmax over size-1 axis == 1.
    float* out = (float*)d_out;

    const int n_rows = in_sizes[0] / C;   // 1,000,000

    // d_out is poisoned to 0xAA before every launch; atomics need zeros.
    hipMemsetAsync(d_out, 0, (size_t)out_size * sizeof(float), stream);

    const int n_waves  = (n_rows + ROWS_PER_WAVE - 1) / ROWS_PER_WAVE;
    const int n_blocks = (n_waves + WAVES_PER_BLOCK - 1) / WAVES_PER_BLOCK;

    segsum_kernel<<<n_blocks, BLOCK_THREADS, 0, stream>>>(
        (const float4*)x, batch, out, n_rows);
}